// Round 3
// baseline (592.240 us; speedup 1.0000x reference)
//
#include <hip/hip_runtime.h>

#define NN 8192
#define CIN 256
#define COUT 128
#define JT 32
#define WLCAP 4096
#define AGG_T 1024
#define BATCH 8
#define GR 16
#define GKT 64

__device__ __forceinline__ float lrelu_exp(float t) {
    return __expf(t >= 0.0f ? t : 0.2f * t);
}

// ---------------- Kernel A: h = x @ W (fp32) + fused a_src/a_dst ----------
// 16 rows/block, 512 blocks (2/CU), 256 threads, thread tile 2x4.
// K-tiled by 64: W tile (64x128, 32 KB) staged in LDS via bulk float4 loads
// (8 in flight/thread), x tile transposed ([k][r], pad 18). Epilogue fuses
// a_src/a_dst row dots with width-32 shfl reduce.
__global__ __launch_bounds__(256) void gemm_h(const float* __restrict__ x,
                                              const float* __restrict__ W,
                                              const float* __restrict__ att_src,
                                              const float* __restrict__ att_dst,
                                              float* __restrict__ h,
                                              float* __restrict__ a_src,
                                              float* __restrict__ a_dst) {
    __shared__ float Wt[GKT * COUT];      // 32 KB
    __shared__ float xt[GKT][GR + 2];     // 4.5 KB, transposed, pad 18
    int tid = threadIdx.x;
    int i0 = blockIdx.x * GR;
    int tx = tid & 31, ty = tid >> 5;
    int c0 = tx * 4, r0 = ty * 2;
    int xr = tid >> 4, xk = (tid & 15) * 4;
    float acc[2][4] = {};

    for (int kt = 0; kt < CIN; kt += GKT) {
        // issue all staging loads first (9 independent float4s in flight)
        float4 wv[8];
        #pragma unroll
        for (int j = 0; j < 8; ++j) {
            int f = j * 256 + tid;   // float4 index within 64x128 tile
            wv[j] = *(const float4*)&W[(size_t)(kt + (f >> 5)) * COUT + (f & 31) * 4];
        }
        float4 xv = *(const float4*)&x[(size_t)(i0 + xr) * CIN + kt + xk];
        __syncthreads();   // previous tile's LDS reads done
        #pragma unroll
        for (int j = 0; j < 8; ++j)
            *(float4*)&Wt[(j * 256 + tid) * 4] = wv[j];
        xt[xk + 0][xr] = xv.x;
        xt[xk + 1][xr] = xv.y;
        xt[xk + 2][xr] = xv.z;
        xt[xk + 3][xr] = xv.w;
        __syncthreads();
        #pragma unroll 8
        for (int k = 0; k < GKT; ++k) {
            float4 wk = *(const float4*)&Wt[k * COUT + c0];
            float2 xf = *(const float2*)&xt[k][r0];
            acc[0][0] += xf.x * wk.x; acc[0][1] += xf.x * wk.y;
            acc[0][2] += xf.x * wk.z; acc[0][3] += xf.x * wk.w;
            acc[1][0] += xf.y * wk.x; acc[1][1] += xf.y * wk.y;
            acc[1][2] += xf.y * wk.z; acc[1][3] += xf.y * wk.w;
        }
    }

    float4 asv = *(const float4*)&att_src[c0];
    float4 adv = *(const float4*)&att_dst[c0];
    #pragma unroll
    for (int a = 0; a < 2; ++a) {
        float4 o = make_float4(acc[a][0], acc[a][1], acc[a][2], acc[a][3]);
        *(float4*)&h[(size_t)(i0 + r0 + a) * COUT + c0] = o;
        float s = o.x * asv.x + o.y * asv.y + o.z * asv.z + o.w * asv.w;
        float d = o.x * adv.x + o.y * adv.y + o.z * adv.z + o.w * adv.w;
        #pragma unroll
        for (int m = 16; m >= 1; m >>= 1) {
            s += __shfl_xor(s, m, 32);
            d += __shfl_xor(d, m, 32);
        }
        if (tx == 0) {
            a_src[i0 + r0 + a] = s;
            a_dst[i0 + r0 + a] = d;
        }
    }
}

// ---------------- Kernel B: scan adj stripe, compact nonzeros, aggregate ----
// Block owns 32 output columns (a 128 B-aligned stripe: every fetched line
// belongs entirely to this block). Scan is batched 8-deep: 8 independent
// uint4 loads in flight per thread (128 KB/CU in flight at 16 waves) before
// any processing -> HBM streaming instead of latency-serialized. a_src is
// staged whole in LDS so the (divergent) nonzero path never touches global
// memory (no vmcnt drain of the prefetch queue). Phase 2 batched by 4.
__global__ __launch_bounds__(AGG_T) void gat_agg(const float* __restrict__ adj,
                                                 const float* __restrict__ h,
                                                 const float* __restrict__ a_src,
                                                 const float* __restrict__ a_dst,
                                                 const float* __restrict__ bias,
                                                 float* __restrict__ out) {
    __shared__ float accS[JT * COUT];       // 16 KB
    __shared__ float asrcS[NN];             // 32 KB
    __shared__ float denomS[JT];
    __shared__ float adstS[JT];
    __shared__ unsigned int wlMeta[WLCAP];  // 16 KB
    __shared__ float wlW[WLCAP];            // 16 KB
    __shared__ int wlcnt;

    int tid = threadIdx.x;
    int j0 = blockIdx.x * JT;

    // stage a_src (8192 floats) as float4s
    {
        float4* dst = (float4*)asrcS;
        const float4* src = (const float4*)a_src;
        dst[tid]        = src[tid];
        dst[tid + 1024] = src[tid + 1024];
    }
    for (int t = tid; t < JT * COUT; t += AGG_T) accS[t] = 0.0f;
    if (tid < JT) { denomS[tid] = 0.0f; adstS[tid] = a_dst[j0 + tid]; }
    if (tid == 0) wlcnt = 0;
    __syncthreads();

    // forced self-loops: added exactly once (real diagonal excluded below)
    if (tid < JT) {
        int i = j0 + tid;
        float w = lrelu_exp(asrcS[i] + adstS[tid]);
        int pos = atomicAdd(&wlcnt, 1);
        wlMeta[pos] = ((unsigned)i << 5) | (unsigned)tid;
        wlW[pos] = w;
        atomicAdd(&denomS[tid], w);
    }

    // scan: lane covers 4 adjacent columns (uint4), 128 rows x BATCH per iter
    int jg = tid & 7;         // column quad 0..7
    int isub = tid >> 3;      // 0..127
    int jbase = jg * 4;
    const float* colbase = adj + j0 + jbase;
    for (int ib = 0; ib < NN; ib += 128 * BATCH) {
        uint4 v[BATCH];
        #pragma unroll
        for (int b = 0; b < BATCH; ++b)
            v[b] = *(const uint4*)(colbase + (size_t)(ib + b * 128 + isub) * NN);
        #pragma unroll
        for (int b = 0; b < BATCH; ++b) {
            if (v[b].x | v[b].y | v[b].z | v[b].w) {
                int i = ib + b * 128 + isub;
                float si = asrcS[i];
                unsigned int vv[4] = {v[b].x, v[b].y, v[b].z, v[b].w};
                #pragma unroll
                for (int q = 0; q < 4; ++q) {
                    if (vv[q] != 0u) {
                        int jl = jbase + q;
                        if (i != j0 + jl) {   // true diagonal handled above
                            float w = __uint_as_float(vv[q]) *
                                      lrelu_exp(si + adstS[jl]);
                            int pos = atomicAdd(&wlcnt, 1);
                            if (pos < WLCAP) {
                                wlMeta[pos] = ((unsigned)i << 5) | (unsigned)jl;
                                wlW[pos] = w;
                            }
                            atomicAdd(&denomS[jl], w);
                        }
                    }
                }
            }
        }
    }
    __syncthreads();

    // phase 2: one wave per entry, batched 4-deep
    int cnt = wlcnt < WLCAP ? wlcnt : WLCAP;
    int wave = tid >> 6, lane = tid & 63;
    for (int e0 = wave * 4; e0 < cnt; e0 += (AGG_T / 64) * 4) {
        int n = cnt - e0; if (n > 4) n = 4;
        unsigned int m[4]; float w[4]; float2 hv[4];
        #pragma unroll
        for (int t = 0; t < 4; ++t) if (t < n) {
            m[t] = wlMeta[e0 + t];
            w[t] = wlW[e0 + t];
        }
        #pragma unroll
        for (int t = 0; t < 4; ++t) if (t < n)
            hv[t] = *(const float2*)&h[(size_t)(m[t] >> 5) * COUT + lane * 2];
        #pragma unroll
        for (int t = 0; t < 4; ++t) if (t < n) {
            int jl = (int)(m[t] & 31u);
            atomicAdd(&accS[jl * COUT + lane * 2],     w[t] * hv[t].x);
            atomicAdd(&accS[jl * COUT + lane * 2 + 1], w[t] * hv[t].y);
        }
    }
    __syncthreads();

    // epilogue: normalize + bias, one float4 per thread
    int jl = tid >> 5;
    int c = (tid & 31) * 4;
    float inv = 1.0f / denomS[jl];
    float4 a = *(const float4*)&accS[jl * COUT + c];
    float4 b = *(const float4*)&bias[c];
    float4 o = make_float4(a.x * inv + b.x, a.y * inv + b.y,
                           a.z * inv + b.z, a.w * inv + b.w);
    *(float4*)&out[(size_t)(j0 + jl) * COUT + c] = o;
}

extern "C" void kernel_launch(void* const* d_in, const int* in_sizes, int n_in,
                              void* d_out, int out_size, void* d_ws, size_t ws_size,
                              hipStream_t stream) {
    const float* x       = (const float*)d_in[0];
    const float* adj     = (const float*)d_in[1];
    const float* W       = (const float*)d_in[2];
    const float* att_src = (const float*)d_in[3];
    const float* att_dst = (const float*)d_in[4];
    const float* bias    = (const float*)d_in[5];
    float* out = (float*)d_out;

    float* h     = (float*)d_ws;                 // 8192*128*4 = 4 MB
    float* a_src = h + (size_t)NN * COUT;        // 32 KB
    float* a_dst = a_src + NN;                   // 32 KB

    gemm_h <<<NN / GR, 256, 0, stream>>>(x, W, att_src, att_dst, h, a_src, a_dst);
    gat_agg<<<NN / JT, AGG_T, 0, stream>>>(adj, h, a_src, a_dst, bias, out);
}